// Round 3
// baseline (222.864 us; speedup 1.0000x reference)
//
#include <hip/hip_runtime.h>

#define LRELU_ALPHA 0.2f

typedef __bf16 bf16x8 __attribute__((ext_vector_type(8)));
typedef unsigned short u16;
typedef unsigned short u16x8 __attribute__((ext_vector_type(8)));
typedef float f32x4 __attribute__((ext_vector_type(4)));
typedef int int4v __attribute__((ext_vector_type(4)));

__device__ __forceinline__ u16 f2bf(float f) {
  unsigned int u = __float_as_uint(f);
  u += 0x7fffu + ((u >> 16) & 1u);   // RNE
  return (u16)(u >> 16);
}

// ---------------- kernel 1: WbT[o][i] = bf16(W[i][o]) ----------------
__global__ __launch_bounds__(256) void wcast(const float* __restrict__ W,
                                             u16* __restrict__ WbT) {
  int idx = blockIdx.x * 256 + threadIdx.x;            // 65536
  WbT[idx] = f2bf(W[(idx & 255) * 256 + (idx >> 8)]);
}

// ---------------- kernel 2: Hh = bf16(h) @ W, fused s/d dots ----------
__global__ __launch_bounds__(256) void gemm1(const float* __restrict__ h,
                                             const u16* __restrict__ WbT,
                                             const float* __restrict__ a,
                                             u16* __restrict__ HhT,
                                             float* __restrict__ sbuf,
                                             float* __restrict__ dbuf) {
  const int tid = threadIdx.x, bid = blockIdx.x;
  const int l = tid & 63, w = tid >> 6;
  const int lr = l & 15;
  const int lk = (l >> 4) << 3;
  const int rowA = bid * 64 + 16 * w + lr;
  const float* hrow = h + (size_t)rowA * 256 + lk;

  f32x4 acc[16];
#pragma unroll
  for (int n = 0; n < 16; ++n) acc[n] = (f32x4){0.f, 0.f, 0.f, 0.f};

  for (int k0 = 0; k0 < 256; k0 += 32) {
    f32x4 a0 = *(const f32x4*)(hrow + k0);
    f32x4 a1 = *(const f32x4*)(hrow + k0 + 4);
    u16x8 au;
    au[0] = f2bf(a0[0]); au[1] = f2bf(a0[1]); au[2] = f2bf(a0[2]); au[3] = f2bf(a0[3]);
    au[4] = f2bf(a1[0]); au[5] = f2bf(a1[1]); au[6] = f2bf(a1[2]); au[7] = f2bf(a1[3]);
    bf16x8 af = __builtin_bit_cast(bf16x8, au);
#pragma unroll
    for (int n = 0; n < 16; ++n) {
      int4v bv = *(const int4v*)(WbT + (size_t)(16 * n + lr) * 256 + k0 + lk);
      bf16x8 bf = __builtin_bit_cast(bf16x8, bv);
      acc[n] = __builtin_amdgcn_mfma_f32_16x16x32_bf16(af, bf, acc[n], 0, 0, 0);
    }
  }

  float sp[4] = {0.f, 0.f, 0.f, 0.f}, dp[4] = {0.f, 0.f, 0.f, 0.f};
#pragma unroll
  for (int n = 0; n < 16; ++n) {
    int col = 16 * n + lr;
    float as = a[col];
    float ad = a[256 + col];
#pragma unroll
    for (int rr = 0; rr < 4; ++rr) {
      int row = bid * 64 + 16 * w + ((l >> 4) << 2) + rr;
      int bb = row >> 12, nl = row & 4095;
      float v = acc[n][rr];
      HhT[((size_t)(bb * 256 + col)) * 4096 + nl] = f2bf(v);
      sp[rr] += v * as;
      dp[rr] += v * ad;
    }
  }
#pragma unroll
  for (int rr = 0; rr < 4; ++rr) {
#pragma unroll
    for (int off = 1; off < 16; off <<= 1) {
      sp[rr] += __shfl_xor(sp[rr], off);
      dp[rr] += __shfl_xor(dp[rr], off);
    }
  }
  if ((l & 15) == 0) {
#pragma unroll
    for (int rr = 0; rr < 4; ++rr) {
      int row = bid * 64 + 16 * w + ((l >> 4) << 2) + rr;
      sbuf[row] = sp[rr];
      dbuf[row] = dp[rr];
    }
  }
}

// ---------------- kernel 3: main fused GAT aggregation ----------------
// grid 512 (2/CU), 256 thr / 4 waves; 32 rows x 256 cols per block.
// A-fragment (e-tile) generated directly in registers (no At LDS, no d_lds).
// Bt double-buffered; distance-4 register prefetch ring; 1 barrier/step.
__global__ __launch_bounds__(256, 2) void gat_main(const int* __restrict__ adj,
                                                   const u16* __restrict__ HhT,
                                                   const float* __restrict__ s,
                                                   const float* __restrict__ d,
                                                   float* __restrict__ out) {
  __shared__ __align__(16) u16 Bt[2][256 * 40];   // stride 40: 2-way (free)
  __shared__ float rs_lds[32];

  const int tid = threadIdx.x;
  const int bid = blockIdx.x;
  // XCD swizzle: batch b -> 2 XCDs so its 2MB HhT panel is L2-resident.
  const int xcd = bid & 7;
  const int b = xcd >> 1;
  const int tile = (bid >> 3) | ((xcd & 1) << 6);   // 0..127
  const int rowbase = tile << 5;

  const int l = tid & 63, w = tid >> 6;
  const int lr = l & 15, lkg = l >> 4, lk = lkg << 3;
  const int row0 = 16 * (w & 1);
  const int colb = 128 * (w >> 1);

  const int myrow = rowbase + row0 + lr;
  const float s_row = s[b * 4096 + myrow];

  // A-path pointers: this thread's 8-int adj chunk / 8-float d chunk per step
  const int4v* aptr = (const int4v*)(adj + ((size_t)(b * 4096 + myrow)) * 4096 + lk);
  const f32x4* dptr = (const f32x4*)(d + b * 4096 + lk);

  // B staging: thread covers cols cr, cr+64, cr+128, cr+192, 16B chunk cp
  const int cr = tid >> 2, cp = tid & 3;
  const int4v* bp0 = (const int4v*)HhT + (((size_t)(b * 256 + cr      )) << 9) + cp;
  const int4v* bp1 = (const int4v*)HhT + (((size_t)(b * 256 + cr +  64)) << 9) + cp;
  const int4v* bp2 = (const int4v*)HhT + (((size_t)(b * 256 + cr + 128)) << 9) + cp;
  const int4v* bp3 = (const int4v*)HhT + (((size_t)(b * 256 + cr + 192)) << 9) + cp;

  f32x4 acc[8];
#pragma unroll
  for (int n = 0; n < 8; ++n) acc[n] = (f32x4){0.f, 0.f, 0.f, 0.f};
  float racc = 0.f;

  // distance-4 prefetch ring: sets S0..S3 hold steps k..k+3
  int4v S0a0, S0a1, S1a0, S1a1, S2a0, S2a1, S3a0, S3a1;
  f32x4 S0d0, S0d1, S1d0, S1d1, S2d0, S2d1, S3d0, S3d1;
  int4v S0b0, S0b1, S0b2, S0b3, S1b0, S1b1, S1b2, S1b3;
  int4v S2b0, S2b1, S2b2, S2b3, S3b0, S3b1, S3b2, S3b3;

#define PREF_B(S, STEP) { const int i_ = (STEP) << 2;                         \
    S##b0 = bp0[i_]; S##b1 = bp1[i_]; S##b2 = bp2[i_]; S##b3 = bp3[i_]; }
#define PREF_AD(S, STEP) { const int i_ = (STEP) << 3;                        \
    S##a0 = aptr[i_]; S##a1 = aptr[i_ + 1];                                   \
    S##d0 = dptr[i_]; S##d1 = dptr[i_ + 1]; }

  PREF_B(S0, 0) PREF_AD(S0, 0)
  PREF_B(S1, 1) PREF_AD(S1, 1)
  PREF_B(S2, 2) PREF_AD(S2, 2)
  PREF_B(S3, 3) PREF_AD(S3, 3)

#define SUBSTEP(BUF, S, NXT)                                                  \
  {                                                                           \
    *(int4v*)&Bt[BUF][(cr      ) * 40 + cp * 8] = S##b0;                      \
    *(int4v*)&Bt[BUF][(cr +  64) * 40 + cp * 8] = S##b1;                      \
    *(int4v*)&Bt[BUF][(cr + 128) * 40 + cp * 8] = S##b2;                      \
    *(int4v*)&Bt[BUF][(cr + 192) * 40 + cp * 8] = S##b3;                      \
    PREF_B(S, NXT)                                                            \
    u16x8 au_;                                                                \
    {                                                                         \
      int aj[8] = {S##a0.x, S##a0.y, S##a0.z, S##a0.w,                        \
                   S##a1.x, S##a1.y, S##a1.z, S##a1.w};                       \
      float dv[8] = {S##d0[0], S##d0[1], S##d0[2], S##d0[3],                  \
                     S##d1[0], S##d1[1], S##d1[2], S##d1[3]};                 \
      _Pragma("unroll")                                                       \
      for (int j = 0; j < 8; ++j) {                                           \
        float lg = s_row + dv[j];                                             \
        float t = fmaxf(lg, LRELU_ALPHA * lg);                                \
        float e = (aj[j] != 0) ? __expf(-t) : 0.f;                            \
        racc += e;                                                            \
        au_[j] = f2bf(e);                                                     \
      }                                                                       \
    }                                                                         \
    PREF_AD(S, NXT)                                                           \
    asm volatile("s_waitcnt lgkmcnt(0)" ::: "memory");                        \
    __builtin_amdgcn_s_barrier();                                             \
    __builtin_amdgcn_sched_barrier(0);                                        \
    {                                                                         \
      bf16x8 af = __builtin_bit_cast(bf16x8, au_);                            \
      __builtin_amdgcn_s_setprio(1);                                          \
      _Pragma("unroll")                                                       \
      for (int n = 0; n < 8; ++n) {                                           \
        bf16x8 bf = __builtin_bit_cast(bf16x8,                                \
            *(const int4v*)&Bt[BUF][(colb + 16 * n + lr) * 40 + lk]);         \
        acc[n] = __builtin_amdgcn_mfma_f32_16x16x32_bf16(af, bf, acc[n],      \
                                                         0, 0, 0);            \
      }                                                                       \
      __builtin_amdgcn_s_setprio(0);                                          \
    }                                                                         \
  }

  for (int k = 0; k < 128; k += 4) {
    int n0 = k + 4, n1 = k + 5, n2 = k + 6, n3 = k + 7;
    if (n0 > 127) n0 = 127;
    if (n1 > 127) n1 = 127;
    if (n2 > 127) n2 = 127;
    if (n3 > 127) n3 = 127;
    SUBSTEP(0, S0, n0)
    SUBSTEP(1, S1, n1)
    SUBSTEP(0, S2, n2)
    SUBSTEP(1, S3, n3)
  }
#undef SUBSTEP
#undef PREF_B
#undef PREF_AD

  // ---- rowsum: lanes sharing lr (lkg partners) hold disjoint partials ----
  racc += __shfl_xor(racc, 16);
  racc += __shfl_xor(racc, 32);
  if (w < 2 && lkg == 0) rs_lds[row0 + lr] = (racc == 0.f) ? 1.f : racc;
  __syncthreads();

  // ---- epilogue: divide + elu + store ----
#pragma unroll
  for (int rr = 0; rr < 4; ++rr) {
    int rin = row0 + (lkg << 2) + rr;
    float inv = 1.f / rs_lds[rin];
    size_t obase = ((size_t)(b * 4096 + rowbase + rin)) * 256 + colb;
#pragma unroll
    for (int n = 0; n < 8; ++n) {
      float v = acc[n][rr] * inv;
      out[obase + 16 * n + lr] = v > 0.f ? v : (__expf(v) - 1.f);
    }
  }
}

extern "C" void kernel_launch(void* const* d_in, const int* in_sizes, int n_in,
                              void* d_out, int out_size, void* d_ws, size_t ws_size,
                              hipStream_t stream) {
  const float* h = (const float*)d_in[0];
  const int* adj = (const int*)d_in[1];
  const float* W = (const float*)d_in[2];
  const float* a = (const float*)d_in[3];
  float* out = (float*)d_out;

  u16* WbT  = (u16*)d_ws;                                  // 128 KB
  u16* HhT  = (u16*)((char*)d_ws + 131072);                // 8 MB
  float* sb = (float*)((char*)d_ws + 131072 + 8388608);    // 64 KB
  float* db = sb + 16384;                                  // 64 KB

  hipLaunchKernelGGL(wcast,    dim3(256), dim3(256), 0, stream, W, WbT);
  hipLaunchKernelGGL(gemm1,    dim3(256), dim3(256), 0, stream, h, WbT, a, HhT, sb, db);
  hipLaunchKernelGGL(gat_main, dim3(512), dim3(256), 0, stream, adj, HhT, sb, db, out);
}

// Round 4
// 196.903 us; speedup vs baseline: 1.1318x; 1.1318x over previous
//
#include <hip/hip_runtime.h>

#define LRELU_ALPHA 0.2f

typedef __bf16 bf16x8 __attribute__((ext_vector_type(8)));
typedef unsigned short u16;
typedef unsigned short u16x8 __attribute__((ext_vector_type(8)));
typedef float f32x4 __attribute__((ext_vector_type(4)));
typedef int int4v __attribute__((ext_vector_type(4)));

__device__ __forceinline__ u16 f2bf(float f) {
  unsigned int u = __float_as_uint(f);
  u += 0x7fffu + ((u >> 16) & 1u);   // RNE
  return (u16)(u >> 16);
}

// async global->LDS, 16B per active lane; dest = wave-uniform base + lane*16
__device__ __forceinline__ void gload16(const void* g, void* lds) {
  __builtin_amdgcn_global_load_lds(
      (const __attribute__((address_space(1))) void*)g,
      (__attribute__((address_space(3))) void*)lds, 16, 0, 0);
}

// ---------------- kernel 1: WbT[o][i] = bf16(W[i][o]) ----------------
__global__ __launch_bounds__(256) void wcast(const float* __restrict__ W,
                                             u16* __restrict__ WbT) {
  int idx = blockIdx.x * 256 + threadIdx.x;            // 65536
  WbT[idx] = f2bf(W[(idx & 255) * 256 + (idx >> 8)]);
}

// ---------------- kernel 2: Hh = bf16(h) @ W, fused s/d dots ----------
__global__ __launch_bounds__(256) void gemm1(const float* __restrict__ h,
                                             const u16* __restrict__ WbT,
                                             const float* __restrict__ a,
                                             u16* __restrict__ HhT,
                                             float* __restrict__ sbuf,
                                             float* __restrict__ dbuf) {
  const int tid = threadIdx.x, bid = blockIdx.x;
  const int l = tid & 63, w = tid >> 6;
  const int lr = l & 15;
  const int lk = (l >> 4) << 3;
  const int rowA = bid * 64 + 16 * w + lr;
  const float* hrow = h + (size_t)rowA * 256 + lk;

  f32x4 acc[16];
#pragma unroll
  for (int n = 0; n < 16; ++n) acc[n] = (f32x4){0.f, 0.f, 0.f, 0.f};

  for (int k0 = 0; k0 < 256; k0 += 32) {
    f32x4 a0 = *(const f32x4*)(hrow + k0);
    f32x4 a1 = *(const f32x4*)(hrow + k0 + 4);
    u16x8 au;
    au[0] = f2bf(a0[0]); au[1] = f2bf(a0[1]); au[2] = f2bf(a0[2]); au[3] = f2bf(a0[3]);
    au[4] = f2bf(a1[0]); au[5] = f2bf(a1[1]); au[6] = f2bf(a1[2]); au[7] = f2bf(a1[3]);
    bf16x8 af = __builtin_bit_cast(bf16x8, au);
#pragma unroll
    for (int n = 0; n < 16; ++n) {
      int4v bv = *(const int4v*)(WbT + (size_t)(16 * n + lr) * 256 + k0 + lk);
      bf16x8 bf = __builtin_bit_cast(bf16x8, bv);
      acc[n] = __builtin_amdgcn_mfma_f32_16x16x32_bf16(af, bf, acc[n], 0, 0, 0);
    }
  }

  float sp[4] = {0.f, 0.f, 0.f, 0.f}, dp[4] = {0.f, 0.f, 0.f, 0.f};
#pragma unroll
  for (int n = 0; n < 16; ++n) {
    int col = 16 * n + lr;
    float as = a[col];
    float ad = a[256 + col];
#pragma unroll
    for (int rr = 0; rr < 4; ++rr) {
      int row = bid * 64 + 16 * w + ((l >> 4) << 2) + rr;
      int bb = row >> 12, nl = row & 4095;
      float v = acc[n][rr];
      HhT[((size_t)(bb * 256 + col)) * 4096 + nl] = f2bf(v);
      sp[rr] += v * as;
      dp[rr] += v * ad;
    }
  }
#pragma unroll
  for (int rr = 0; rr < 4; ++rr) {
#pragma unroll
    for (int off = 1; off < 16; off <<= 1) {
      sp[rr] += __shfl_xor(sp[rr], off);
      dp[rr] += __shfl_xor(dp[rr], off);
    }
  }
  if ((l & 15) == 0) {
#pragma unroll
    for (int rr = 0; rr < 4; ++rr) {
      int row = bid * 64 + 16 * w + ((l >> 4) << 2) + rr;
      sbuf[row] = sp[rr];
      dbuf[row] = dp[rr];
    }
  }
}

// ---------------- kernel 3: main fused GAT aggregation ----------------
// grid 512 (2/CU), 256 thr / 4 waves; 32 rows x 256 cols per block.
// All staging via global_load_lds (unsinkable, VGPR-free), 3-buffer ring,
// counted vmcnt(6), one raw s_barrier per step. Rule-21 both-sides swizzle:
//   Bt: LDS[col*64 + c*16] holds global chunk c ^ ((col>>1)&3)  (2-way free)
//   At: LDS[row*128 + c*16] holds global chunk c ^ (row&7)      (2-way free)
__global__ __launch_bounds__(256, 2) void gat_main(const int* __restrict__ adj,
                                                   const u16* __restrict__ HhT,
                                                   const float* __restrict__ s,
                                                   const float* __restrict__ d,
                                                   float* __restrict__ out) {
  __shared__ __align__(16) u16 Bt[3][8192];   // [buf][col*32 + chunk*8] (16 KB/buf)
  __shared__ __align__(16) int At[3][1024];   // [buf][row*32 + chunk*4] (4 KB/buf)
  __shared__ __align__(16) float Dt[3][32];   // [buf][32 k-values]
  __shared__ float rs_lds[32];

  const int tid = threadIdx.x, bid = blockIdx.x;
  // XCD swizzle: batch b -> 2 XCDs so its 2MB HhT panel is L2-resident.
  const int xcd = bid & 7;
  const int b = xcd >> 1;
  const int tile = (bid >> 3) | ((xcd & 1) << 6);   // 0..127
  const int rowbase = tile << 5;

  const int l = tid & 63, w = tid >> 6;
  const int lr = l & 15, lkg = l >> 4;
  const int row0 = 16 * (w & 1);
  const int colb = 128 * (w >> 1);

  const int myrow = rowbase + row0 + lr;
  const float s_row = s[b * 4096 + myrow];

  // ---- DMA source addresses (pre-swizzled per rule 21) ----
  // B: wave w, issue i covers cols (w*4+i)*16 .. +16; lane: col=g*16+(l>>2),
  //    dest chunk c=l&3 sources global chunk c ^ ((col>>1)&3) = c ^ ((l>>3)&3)
  const char* HhTb = (const char*)HhT + (size_t)b * 2097152;
  const int colg0 = (w * 4) * 16 + (l >> 2);
  const int csB = (l & 3) ^ ((l >> 3) & 3);
  const char* bsrcBase = HhTb + (size_t)colg0 * 8192 + csB * 16;
  // A: wave w covers rows w*8..w*8+8; lane: row=w*8+(l>>3), chunk c=l&7
  //    sources global chunk c ^ (row&7) = c ^ (l>>3)
  const int csA = (l & 7) ^ (l >> 3);
  const char* asrc = (const char*)adj +
      ((size_t)(b * 4096 + rowbase + w * 8 + (l >> 3))) * 16384 + csA * 16;
  // D: lanes 0-7 stage 32 floats (all 4 waves duplicate -> benign, uniform count)
  const char* dsrc = (const char*)d + (size_t)b * 16384 + (l & 7) * 16;

  char* BtB = (char*)&Bt[0][0];
  char* AtB = (char*)&At[0][0];
  char* DtB = (char*)&Dt[0][0];

  // ---- LDS read offsets (swizzled) ----
  const int atoff0 = (row0 + lr) * 128 + (((2 * lkg) ^ (lr & 7)) * 16);
  const int atoff1 = (row0 + lr) * 128 + (((2 * lkg + 1) ^ (lr & 7)) * 16);
  const int btbase = (colb + lr) * 64 + ((lkg ^ ((lr >> 1) & 3)) * 16);
  const int dtoff = lkg * 32;

  f32x4 acc[8];
#pragma unroll
  for (int n = 0; n < 8; ++n) acc[n] = (f32x4){0.f, 0.f, 0.f, 0.f};
  float racc = 0.f;

#define ISSUE(NXT, STEP)                                                      \
  {                                                                           \
    const size_t bo_ = (size_t)(STEP) * 64;                                   \
    const size_t ao_ = (size_t)(STEP) * 128;                                  \
    gload16(bsrcBase + bo_,          BtB + (NXT) * 16384 + (w * 4 + 0) * 1024); \
    gload16(bsrcBase + bo_ + 131072, BtB + (NXT) * 16384 + (w * 4 + 1) * 1024); \
    gload16(bsrcBase + bo_ + 262144, BtB + (NXT) * 16384 + (w * 4 + 2) * 1024); \
    gload16(bsrcBase + bo_ + 393216, BtB + (NXT) * 16384 + (w * 4 + 3) * 1024); \
    gload16(asrc + ao_,              AtB + (NXT) * 4096 + w * 1024);          \
    if (l < 8) gload16(dsrc + ao_,   DtB + (NXT) * 128);                      \
  }

#define COMPUTE(CUR)                                                          \
  {                                                                           \
    int4v aA = *(const int4v*)(AtB + (CUR) * 4096 + atoff0);                  \
    int4v aB = *(const int4v*)(AtB + (CUR) * 4096 + atoff1);                  \
    f32x4 dA = *(const f32x4*)(DtB + (CUR) * 128 + dtoff);                    \
    f32x4 dB = *(const f32x4*)(DtB + (CUR) * 128 + dtoff + 16);               \
    u16x8 au_;                                                                \
    {                                                                         \
      int aj[8] = {aA.x, aA.y, aA.z, aA.w, aB.x, aB.y, aB.z, aB.w};           \
      float dv[8] = {dA[0], dA[1], dA[2], dA[3], dB[0], dB[1], dB[2], dB[3]}; \
      _Pragma("unroll")                                                       \
      for (int j = 0; j < 8; ++j) {                                           \
        float lg = s_row + dv[j];                                             \
        float t = fmaxf(lg, LRELU_ALPHA * lg);                                \
        float e = (aj[j] != 0) ? __expf(-t) : 0.f;                            \
        racc += e;                                                            \
        au_[j] = f2bf(e);                                                     \
      }                                                                       \
    }                                                                         \
    bf16x8 af = __builtin_bit_cast(bf16x8, au_);                              \
    _Pragma("unroll")                                                         \
    for (int n = 0; n < 8; ++n) {                                             \
      bf16x8 bfv = __builtin_bit_cast(bf16x8,                                 \
          *(const int4v*)(BtB + (CUR) * 16384 + btbase + n * 1024));          \
      acc[n] = __builtin_amdgcn_mfma_f32_16x16x32_bf16(af, bfv, acc[n],       \
                                                       0, 0, 0);              \
    }                                                                         \
  }

  // prologue: stage steps 0,1; publish step 0
  ISSUE(0, 0)
  ISSUE(1, 1)
  asm volatile("s_waitcnt vmcnt(6)" ::: "memory");
  __builtin_amdgcn_s_barrier();

  // steady state: per step issue 6 DMAs (step k+2), compute buf k%3,
  // drain lgkm (my reads), vmcnt(6) (publishes buf k+1), barrier.
  for (int k = 0; k < 126; k += 3) {
    ISSUE(2, k + 2)
    COMPUTE(0)
    asm volatile("s_waitcnt lgkmcnt(0)" ::: "memory");
    asm volatile("s_waitcnt vmcnt(6)" ::: "memory");
    __builtin_amdgcn_s_barrier();

    ISSUE(0, k + 3)
    COMPUTE(1)
    asm volatile("s_waitcnt lgkmcnt(0)" ::: "memory");
    asm volatile("s_waitcnt vmcnt(6)" ::: "memory");
    __builtin_amdgcn_s_barrier();

    ISSUE(1, k + 4)
    COMPUTE(2)
    asm volatile("s_waitcnt lgkmcnt(0)" ::: "memory");
    asm volatile("s_waitcnt vmcnt(6)" ::: "memory");
    __builtin_amdgcn_s_barrier();
  }
  // tail: steps 126 (buf0), 127 (buf1) — no further issues
  COMPUTE(0)
  asm volatile("s_waitcnt lgkmcnt(0)" ::: "memory");
  asm volatile("s_waitcnt vmcnt(0)" ::: "memory");
  __builtin_amdgcn_s_barrier();
  COMPUTE(1)
#undef ISSUE
#undef COMPUTE

  // ---- rowsum: partials live in lkg partners; waves 0,1 own the rows ----
  racc += __shfl_xor(racc, 16);
  racc += __shfl_xor(racc, 32);
  if (w < 2 && lkg == 0) rs_lds[row0 + lr] = (racc == 0.f) ? 1.f : racc;
  __syncthreads();

  // ---- epilogue: divide + elu + store ----
#pragma unroll
  for (int rr = 0; rr < 4; ++rr) {
    int rin = row0 + (lkg << 2) + rr;
    float inv = 1.f / rs_lds[rin];
    size_t obase = ((size_t)(b * 4096 + rowbase + rin)) * 256 + colb;
#pragma unroll
    for (int n = 0; n < 8; ++n) {
      float v = acc[n][rr] * inv;
      out[obase + 16 * n + lr] = v > 0.f ? v : (__expf(v) - 1.f);
    }
  }
}

extern "C" void kernel_launch(void* const* d_in, const int* in_sizes, int n_in,
                              void* d_out, int out_size, void* d_ws, size_t ws_size,
                              hipStream_t stream) {
  const float* h = (const float*)d_in[0];
  const int* adj = (const int*)d_in[1];
  const float* W = (const float*)d_in[2];
  const float* a = (const float*)d_in[3];
  float* out = (float*)d_out;

  u16* WbT  = (u16*)d_ws;                                  // 128 KB
  u16* HhT  = (u16*)((char*)d_ws + 131072);                // 8 MB
  float* sb = (float*)((char*)d_ws + 131072 + 8388608);    // 64 KB
  float* db = sb + 16384;                                  // 64 KB

  hipLaunchKernelGGL(wcast,    dim3(256), dim3(256), 0, stream, W, WbT);
  hipLaunchKernelGGL(gemm1,    dim3(256), dim3(256), 0, stream, h, WbT, a, HhT, sb, db);
  hipLaunchKernelGGL(gat_main, dim3(512), dim3(256), 0, stream, adj, HhT, sb, db, out);
}

// Round 5
// 176.213 us; speedup vs baseline: 1.2647x; 1.1174x over previous
//
#include <hip/hip_runtime.h>

#define LRELU_ALPHA 0.2f

typedef __bf16 bf16x8 __attribute__((ext_vector_type(8)));
typedef unsigned short u16;
typedef unsigned short u16x8 __attribute__((ext_vector_type(8)));
typedef float f32x4 __attribute__((ext_vector_type(4)));
typedef int int4v __attribute__((ext_vector_type(4)));

__device__ __forceinline__ u16 f2bf(float f) {
  unsigned int u = __float_as_uint(f);
  u += 0x7fffu + ((u >> 16) & 1u);   // RNE
  return (u16)(u >> 16);
}

// async global->LDS, 16B per active lane; dest = wave-uniform base + lane*16
__device__ __forceinline__ void gload16(const void* g, void* lds) {
  __builtin_amdgcn_global_load_lds(
      (const __attribute__((address_space(1))) void*)g,
      (__attribute__((address_space(3))) void*)lds, 16, 0, 0);
}

// ---------------- kernel 1: WbT[o][i] = bf16(W[i][o]) ----------------
__global__ __launch_bounds__(256) void wcast(const float* __restrict__ W,
                                             u16* __restrict__ WbT) {
  int idx = blockIdx.x * 256 + threadIdx.x;            // 65536
  WbT[idx] = f2bf(W[(idx & 255) * 256 + (idx >> 8)]);
}

// ---------------- kernel 2: Hh = bf16(h) @ W, fused s/d dots ----------
__global__ __launch_bounds__(256) void gemm1(const float* __restrict__ h,
                                             const u16* __restrict__ WbT,
                                             const float* __restrict__ a,
                                             u16* __restrict__ HhT,
                                             float* __restrict__ sbuf,
                                             float* __restrict__ dbuf) {
  const int tid = threadIdx.x, bid = blockIdx.x;
  const int l = tid & 63, w = tid >> 6;
  const int lr = l & 15;
  const int lk = (l >> 4) << 3;
  const int rowA = bid * 64 + 16 * w + lr;
  const float* hrow = h + (size_t)rowA * 256 + lk;

  f32x4 acc[16];
#pragma unroll
  for (int n = 0; n < 16; ++n) acc[n] = (f32x4){0.f, 0.f, 0.f, 0.f};

  for (int k0 = 0; k0 < 256; k0 += 32) {
    f32x4 a0 = *(const f32x4*)(hrow + k0);
    f32x4 a1 = *(const f32x4*)(hrow + k0 + 4);
    u16x8 au;
    au[0] = f2bf(a0[0]); au[1] = f2bf(a0[1]); au[2] = f2bf(a0[2]); au[3] = f2bf(a0[3]);
    au[4] = f2bf(a1[0]); au[5] = f2bf(a1[1]); au[6] = f2bf(a1[2]); au[7] = f2bf(a1[3]);
    bf16x8 af = __builtin_bit_cast(bf16x8, au);
#pragma unroll
    for (int n = 0; n < 16; ++n) {
      int4v bv = *(const int4v*)(WbT + (size_t)(16 * n + lr) * 256 + k0 + lk);
      bf16x8 bf = __builtin_bit_cast(bf16x8, bv);
      acc[n] = __builtin_amdgcn_mfma_f32_16x16x32_bf16(af, bf, acc[n], 0, 0, 0);
    }
  }

  float sp[4] = {0.f, 0.f, 0.f, 0.f}, dp[4] = {0.f, 0.f, 0.f, 0.f};
#pragma unroll
  for (int n = 0; n < 16; ++n) {
    int col = 16 * n + lr;
    float as = a[col];
    float ad = a[256 + col];
#pragma unroll
    for (int rr = 0; rr < 4; ++rr) {
      int row = bid * 64 + 16 * w + ((l >> 4) << 2) + rr;
      int bb = row >> 12, nl = row & 4095;
      float v = acc[n][rr];
      HhT[((size_t)(bb * 256 + col)) * 4096 + nl] = f2bf(v);
      sp[rr] += v * as;
      dp[rr] += v * ad;
    }
  }
#pragma unroll
  for (int rr = 0; rr < 4; ++rr) {
#pragma unroll
    for (int off = 1; off < 16; off <<= 1) {
      sp[rr] += __shfl_xor(sp[rr], off);
      dp[rr] += __shfl_xor(dp[rr], off);
    }
  }
  if ((l & 15) == 0) {
#pragma unroll
    for (int rr = 0; rr < 4; ++rr) {
      int row = bid * 64 + 16 * w + ((l >> 4) << 2) + rr;
      sbuf[row] = sp[rr];
      dbuf[row] = dp[rr];
    }
  }
}

// ---------------- kernel 3: main fused GAT aggregation ----------------
// grid 256 (1/CU), 512 thr / 8 waves; 64 rows x 256 cols per block.
// 4-buffer ring, issue distance 3, counted vmcnt(8); 4 DMAs/wave/step
// (uniform). R4-verified both-sides swizzles for Bt and At.
__global__ __launch_bounds__(512, 2) void gat_main(const int* __restrict__ adj,
                                                   const u16* __restrict__ HhT,
                                                   const float* __restrict__ s,
                                                   const float* __restrict__ d,
                                                   float* __restrict__ out) {
  __shared__ __align__(16) u16 Bt4[4][8192];   // [buf][col*32 + c*8], 16 KB/buf
  __shared__ __align__(16) int At4[4][2048];   // [buf][row*32 + c*4], 8 KB/buf
  __shared__ __align__(16) float Dt4[4][32];   // [buf][32 k-values]
  __shared__ float rs_lds[64];

  const int tid = threadIdx.x, bid = blockIdx.x;
  // XCD-chunked bijective swizzle: 256 blocks, 32/XCD; batch = 2 XCDs.
  const int xcd = bid & 7;
  const int t256 = (xcd << 5) | (bid >> 3);    // 0..255
  const int b = t256 >> 6;
  const int rowbase = (t256 & 63) << 6;

  const int l = tid & 63, w = tid >> 6;        // w 0..7
  const int wr = w & 3, wc = w >> 2;
  const int lr = l & 15, lkg = l >> 4;
  const int rowt = 16 * wr + lr;               // tile row for A-frag / e-gen
  const float s_row = s[b * 4096 + rowbase + rowt];

  // ---- DMA sources (pre-swizzled; same scheme as R4, correctness-proven) ----
  const char* HhTb = (const char*)HhT + (size_t)b * 2097152;
  const int csB = (l & 3) ^ ((l >> 3) & 3);
  const char* bsrc0 = HhTb + (size_t)(w * 32 +      (l >> 2)) * 8192 + csB * 16;
  const char* bsrc1 = HhTb + (size_t)(w * 32 + 16 + (l >> 2)) * 8192 + csB * 16;
  const int csA = (l & 7) ^ (l >> 3);
  const char* asrc = (const char*)adj +
      ((size_t)(b * 4096 + rowbase + w * 8 + (l >> 3))) * 16384 + csA * 16;
  const char* dsrc = (const char*)d + (size_t)b * 16384 + w * 16;

  char* BtB = (char*)&Bt4[0][0];
  char* AtB = (char*)&At4[0][0];
  char* DtB = (char*)&Dt4[0][0];

  // ---- LDS read offsets (swizzled, matching the writes) ----
  const int atoff0 = rowt * 128 + (((2 * lkg)     ^ (lr & 7)) * 16);
  const int atoff1 = rowt * 128 + (((2 * lkg + 1) ^ (lr & 7)) * 16);
  const int btbase = (128 * wc + lr) * 64 + ((lkg ^ ((lr >> 1) & 3)) * 16);
  const int dtoff = lkg * 32;

  f32x4 acc[8];
#pragma unroll
  for (int n = 0; n < 8; ++n) acc[n] = (f32x4){0.f, 0.f, 0.f, 0.f};
  float racc = 0.f;

#define ISSUE(NXT, STEP)                                                      \
  {                                                                           \
    const size_t st_ = (size_t)(STEP);                                        \
    gload16(bsrc0 + st_ * 64,  BtB + (NXT) * 16384 + (w * 2 + 0) * 1024);     \
    gload16(bsrc1 + st_ * 64,  BtB + (NXT) * 16384 + (w * 2 + 1) * 1024);     \
    gload16(asrc + st_ * 128,  AtB + (NXT) * 8192 + w * 1024);                \
    if (l == 0) gload16(dsrc + st_ * 128, DtB + (NXT) * 128 + w * 16);        \
  }

#define COMPUTE(CUR)                                                          \
  {                                                                           \
    int4v aA = *(const int4v*)(AtB + (CUR) * 8192 + atoff0);                  \
    int4v aB = *(const int4v*)(AtB + (CUR) * 8192 + atoff1);                  \
    f32x4 dA = *(const f32x4*)(DtB + (CUR) * 128 + dtoff);                    \
    f32x4 dB = *(const f32x4*)(DtB + (CUR) * 128 + dtoff + 16);               \
    u16x8 au_;                                                                \
    {                                                                         \
      int aj[8] = {aA.x, aA.y, aA.z, aA.w, aB.x, aB.y, aB.z, aB.w};           \
      float dv[8] = {dA[0], dA[1], dA[2], dA[3], dB[0], dB[1], dB[2], dB[3]}; \
      _Pragma("unroll")                                                       \
      for (int j = 0; j < 8; ++j) {                                           \
        float lg = s_row + dv[j];                                             \
        float t = fmaxf(lg, LRELU_ALPHA * lg);                                \
        float e = (aj[j] != 0) ? __expf(-t) : 0.f;                            \
        racc += e;                                                            \
        au_[j] = f2bf(e);                                                     \
      }                                                                       \
    }                                                                         \
    bf16x8 af = __builtin_bit_cast(bf16x8, au_);                              \
    __builtin_amdgcn_s_setprio(1);                                            \
    _Pragma("unroll")                                                         \
    for (int n = 0; n < 8; ++n) {                                             \
      bf16x8 bfv = __builtin_bit_cast(bf16x8,                                 \
          *(const int4v*)(BtB + (CUR) * 16384 + btbase + n * 1024));          \
      acc[n] = __builtin_amdgcn_mfma_f32_16x16x32_bf16(af, bfv, acc[n],       \
                                                       0, 0, 0);              \
    }                                                                         \
    __builtin_amdgcn_s_setprio(0);                                            \
  }

#define WAITS(VN)                                                             \
    asm volatile("s_waitcnt lgkmcnt(0)" ::: "memory");                        \
    asm volatile("s_waitcnt vmcnt(" #VN ")" ::: "memory");                    \
    __builtin_amdgcn_s_barrier();

  // prologue: stage steps 0,1,2 (12 DMAs/wave); publish buf0
  ISSUE(0, 0)
  ISSUE(1, 1)
  ISSUE(2, 2)
  asm volatile("s_waitcnt vmcnt(8)" ::: "memory");
  __builtin_amdgcn_s_barrier();

  // steady state: step j computes buf j&3, issues step j+3 into buf (j+3)&3
  // (= buf (j-1)&3, safe: its readers drained before the previous barrier).
  // vmcnt(8) leaves only steps j+2, j+3 in flight -> buf j+1 complete.
  for (int k = 0; k < 124; k += 4) {
    ISSUE(3, k + 3) COMPUTE(0) WAITS(8)
    ISSUE(0, k + 4) COMPUTE(1) WAITS(8)
    ISSUE(1, k + 5) COMPUTE(2) WAITS(8)
    ISSUE(2, k + 6) COMPUTE(3) WAITS(8)
  }
  // steps 124..127
  ISSUE(3, 127) COMPUTE(0) WAITS(8)
  COMPUTE(1) WAITS(4)
  COMPUTE(2) WAITS(0)
  COMPUTE(3)
#undef ISSUE
#undef COMPUTE
#undef WAITS

  // ---- rowsum: reduce lkg partials; wc=0 waves own the write ----
  racc += __shfl_xor(racc, 16);
  racc += __shfl_xor(racc, 32);
  if (wc == 0 && l < 16) rs_lds[16 * wr + l] = (racc == 0.f) ? 1.f : racc;
  __syncthreads();

  // ---- epilogue: divide + elu + store ----
#pragma unroll
  for (int rr = 0; rr < 4; ++rr) {
    int rin = 16 * wr + (lkg << 2) + rr;
    float inv = 1.f / rs_lds[rin];
    size_t obase = ((size_t)(b * 4096 + rowbase + rin)) * 256 + 128 * wc;
#pragma unroll
    for (int n = 0; n < 8; ++n) {
      float v = acc[n][rr] * inv;
      out[obase + 16 * n + lr] = v > 0.f ? v : (__expf(v) - 1.f);
    }
  }
}

extern "C" void kernel_launch(void* const* d_in, const int* in_sizes, int n_in,
                              void* d_out, int out_size, void* d_ws, size_t ws_size,
                              hipStream_t stream) {
  const float* h = (const float*)d_in[0];
  const int* adj = (const int*)d_in[1];
  const float* W = (const float*)d_in[2];
  const float* a = (const float*)d_in[3];
  float* out = (float*)d_out;

  u16* WbT  = (u16*)d_ws;                                  // 128 KB
  u16* HhT  = (u16*)((char*)d_ws + 131072);                // 8 MB
  float* sb = (float*)((char*)d_ws + 131072 + 8388608);    // 64 KB
  float* db = sb + 16384;                                  // 64 KB

  hipLaunchKernelGGL(wcast,    dim3(256), dim3(256), 0, stream, W, WbT);
  hipLaunchKernelGGL(gemm1,    dim3(256), dim3(256), 0, stream, h, WbT, a, HhT, sb, db);
  hipLaunchKernelGGL(gat_main, dim3(256), dim3(512), 0, stream, adj, HhT, sb, db, out);
}

// Round 6
// 165.776 us; speedup vs baseline: 1.3444x; 1.0630x over previous
//
#include <hip/hip_runtime.h>

#define LRELU_ALPHA 0.2f

typedef __bf16 bf16x8 __attribute__((ext_vector_type(8)));
typedef unsigned short u16;
typedef unsigned short u16x4v __attribute__((ext_vector_type(4)));
typedef unsigned short u16x8 __attribute__((ext_vector_type(8)));
typedef float f32x4 __attribute__((ext_vector_type(4)));
typedef int int4v __attribute__((ext_vector_type(4)));
typedef unsigned int u32;

__device__ __forceinline__ u16 f2bf(float f) {
  unsigned int u = __float_as_uint(f);
  u += 0x7fffu + ((u >> 16) & 1u);   // RNE
  return (u16)(u >> 16);
}

// async global->LDS, 16B per lane; dest = wave-uniform base + lane*16
__device__ __forceinline__ void gload16(const void* g, void* lds) {
  __builtin_amdgcn_global_load_lds(
      (const __attribute__((address_space(1))) void*)g,
      (__attribute__((address_space(3))) void*)lds, 16, 0, 0);
}

// ---------------- kernel 1: WbT[o][i] = bf16(W[i][o]) ----------------
__global__ __launch_bounds__(256) void wcast(const float* __restrict__ W,
                                             u16* __restrict__ WbT) {
  int idx = blockIdx.x * 256 + threadIdx.x;            // 65536
  WbT[idx] = f2bf(W[(idx & 255) * 256 + (idx >> 8)]);
}

// ---------------- kernel 2: pack adj to 1-bit mask, row-major stream --
// grid 2048, block 256; each block packs 8 rows (row-major coalesced).
__global__ __launch_bounds__(256) void packadj(const int* __restrict__ adj,
                                               u32* __restrict__ maskg) {
  __shared__ unsigned char nib[1024];
  const int tid = threadIdx.x;
  const size_t row0 = (size_t)blockIdx.x * 8;
  for (int rr = 0; rr < 8; ++rr) {
    const size_t row = row0 + rr;
    const int* arow = adj + row * 4096;
    for (int it = 0; it < 4; ++it) {
      int4v v = *(const int4v*)(arow + it * 1024 + tid * 4);
      unsigned char nb = (unsigned char)((v.x != 0) | ((v.y != 0) << 1) |
                                         ((v.z != 0) << 2) | ((v.w != 0) << 3));
      nib[tid] = nb;
      __syncthreads();
      if (tid < 32) {
        const u32* nw = (const u32*)nib;
        u32 w0 = nw[tid * 2], w1 = nw[tid * 2 + 1];
        u32 m = (w0 & 0xFu) | ((w0 >> 4) & 0xF0u) | ((w0 >> 8) & 0xF00u) |
                ((w0 >> 12) & 0xF000u);
        m |= ((w1 & 0xFu) | ((w1 >> 4) & 0xF0u) | ((w1 >> 8) & 0xF00u) |
              ((w1 >> 12) & 0xF000u)) << 16;
        maskg[row * 128 + it * 32 + tid] = m;
      }
      __syncthreads();
    }
  }
}

// ---------------- kernel 3: Hh = bf16(h) @ W, fused s/d dots ----------
// Writes HhTt in DMA-friendly tiled layout:
// addr_u16(b,col,k) = b*1048576 + (k>>5)*8192 + (col>>4)*512
//                     + ((k>>3)&3)*128 + (col&15)*8 + (k&7)
__global__ __launch_bounds__(256) void gemm1(const float* __restrict__ h,
                                             const u16* __restrict__ WbT,
                                             const float* __restrict__ a,
                                             u16* __restrict__ HhTt,
                                             float* __restrict__ sbuf,
                                             float* __restrict__ dbuf) {
  const int tid = threadIdx.x, bid = blockIdx.x;
  const int l = tid & 63, w = tid >> 6;
  const int lr = l & 15;
  const int lk = (l >> 4) << 3;
  const int rowA = bid * 64 + 16 * w + lr;
  const float* hrow = h + (size_t)rowA * 256 + lk;

  f32x4 acc[16];
#pragma unroll
  for (int n = 0; n < 16; ++n) acc[n] = (f32x4){0.f, 0.f, 0.f, 0.f};

  for (int k0 = 0; k0 < 256; k0 += 32) {
    f32x4 a0 = *(const f32x4*)(hrow + k0);
    f32x4 a1 = *(const f32x4*)(hrow + k0 + 4);
    u16x8 au;
    au[0] = f2bf(a0[0]); au[1] = f2bf(a0[1]); au[2] = f2bf(a0[2]); au[3] = f2bf(a0[3]);
    au[4] = f2bf(a1[0]); au[5] = f2bf(a1[1]); au[6] = f2bf(a1[2]); au[7] = f2bf(a1[3]);
    bf16x8 af = __builtin_bit_cast(bf16x8, au);
#pragma unroll
    for (int n = 0; n < 16; ++n) {
      int4v bv = *(const int4v*)(WbT + (size_t)(16 * n + lr) * 256 + k0 + lk);
      bf16x8 bf = __builtin_bit_cast(bf16x8, bv);
      acc[n] = __builtin_amdgcn_mfma_f32_16x16x32_bf16(af, bf, acc[n], 0, 0, 0);
    }
  }

  float sp[4] = {0.f, 0.f, 0.f, 0.f}, dp[4] = {0.f, 0.f, 0.f, 0.f};
#pragma unroll
  for (int n = 0; n < 16; ++n) {
    int col = 16 * n + lr;
    float as = a[col];
    float ad = a[256 + col];
#pragma unroll
    for (int rr = 0; rr < 4; ++rr) {
      int row = bid * 64 + 16 * w + ((l >> 4) << 2) + rr;
      int bb = row >> 12, kk = row & 4095;
      float v = acc[n][rr];
      size_t addr = (size_t)bb * 1048576 + (size_t)(kk >> 5) * 8192 +
                    (col >> 4) * 512 + ((kk >> 3) & 3) * 128 + (col & 15) * 8 +
                    (kk & 7);
      HhTt[addr] = f2bf(v);
      sp[rr] += v * as;
      dp[rr] += v * ad;
    }
  }
#pragma unroll
  for (int rr = 0; rr < 4; ++rr) {
#pragma unroll
    for (int off = 1; off < 16; off <<= 1) {
      sp[rr] += __shfl_xor(sp[rr], off);
      dp[rr] += __shfl_xor(dp[rr], off);
    }
  }
  if ((l & 15) == 0) {
#pragma unroll
    for (int rr = 0; rr < 4; ++rr) {
      int row = bid * 64 + 16 * w + ((l >> 4) << 2) + rr;
      sbuf[row] = sp[rr];
      dbuf[row] = dp[rr];
    }
  }
}

// ---------------- kernel 4: main fused GAT aggregation ----------------
// grid 256 (1/CU), 512 thr / 8 waves; 64 rows x 256 cols per block.
// No adj traffic in K-loop: mask panel (32KB) + d (16KB) in LDS.
// B via contiguous-1KB DMAs, 4-buf ring, vmcnt(4); e-gen deduped via
// double-buffered At tile. One barrier per step.
__global__ __launch_bounds__(512, 2) void gat_main(const u32* __restrict__ maskg,
                                                   const u16* __restrict__ HhTt,
                                                   const float* __restrict__ s,
                                                   const float* __restrict__ d,
                                                   float* __restrict__ out) {
  __shared__ __align__(16) u16 Bt[4][8192];    // 64 KB: [buf][KB16][1KB linear]
  __shared__ __align__(16) u16 At[2][2048];    // 8 KB: [buf][row64][k32]
  __shared__ __align__(16) u32 Mk[8192];       // 32 KB: [row64][word128] rotated
  __shared__ __align__(16) float Dl[4096];     // 16 KB
  __shared__ float rs_lds[64];

  const int tid = threadIdx.x, bid = blockIdx.x;
  const int xcd = bid & 7;
  const int t256 = (xcd << 5) | (bid >> 3);    // bijective, batch -> 2 XCDs
  const int b = t256 >> 6;
  const int rowbase = (t256 & 63) << 6;

  const int l = tid & 63, w = tid >> 6;        // w 0..7
  const int lr = l & 15, lkg = l >> 4;
  const int wr = w & 1, wc = w >> 1;           // 2 row-halves x 4 col-quads

  // ---- prologue staging: d + rotated mask panel ----
  for (int i = tid; i < 1024; i += 512)
    *(f32x4*)&Dl[i * 4] = *(const f32x4*)(d + b * 4096 + i * 4);
  {
    const u32* mrow = maskg + (size_t)(b * 4096 + rowbase) * 128;
    int r = tid >> 3, w0 = (tid & 7) * 16;
#pragma unroll
    for (int j = 0; j < 16; ++j) {
      int ww = w0 + j;
      Mk[r * 128 + ((ww + r) & 127)] = mrow[r * 128 + ww];
    }
  }

  // ---- e-gen mapping: thread covers (row er, k-chunk c8 of 4) ----
  const int er = tid >> 3, c8 = tid & 7;
  const float s_e = s[b * 4096 + rowbase + er];

  // ---- B DMA sources (1 KB contiguous per wave-DMA) ----
  const char* bsrc0 = (const char*)HhTt +
      ((size_t)b * 1048576 + (2 * w + 0) * 512 + l * 8) * 2;
  const char* bsrc1 = (const char*)HhTt +
      ((size_t)b * 1048576 + (2 * w + 1) * 512 + l * 8) * 2;
  char* BtB = (char*)&Bt[0][0];

  // ---- LDS read offsets (u16 units) ----
  const int atoff0 = (32 * wr + lr) * 32 + lkg * 8;
  const int atoff1 = (32 * wr + 16 + lr) * 32 + lkg * 8;
  const int btoff = 4 * wc * 512 + lkg * 128 + lr * 8;   // + n*512

  f32x4 acc0[4], acc1[4];
#pragma unroll
  for (int n = 0; n < 4; ++n) {
    acc0[n] = (f32x4){0.f, 0.f, 0.f, 0.f};
    acc1[n] = (f32x4){0.f, 0.f, 0.f, 0.f};
  }
  float racc = 0.f;

#define ISSUE(BUF, STEP)                                                      \
  {                                                                           \
    const size_t so_ = (size_t)(STEP) * 16384;                                \
    gload16(bsrc0 + so_, BtB + (BUF) * 16384 + (2 * w + 0) * 1024);           \
    gload16(bsrc1 + so_, BtB + (BUF) * 16384 + (2 * w + 1) * 1024);           \
  }

#define EGEN(BUFA, STEP)                                                      \
  {                                                                           \
    const int st_ = (STEP);                                                   \
    u32 mword = Mk[er * 128 + ((st_ + er) & 127)];                            \
    u32 m8 = mword >> (c8 * 4);                                               \
    f32x4 dv = *(const f32x4*)&Dl[st_ * 32 + c8 * 4];                         \
    u16x4v ev;                                                                \
    _Pragma("unroll")                                                         \
    for (int j = 0; j < 4; ++j) {                                             \
      float lg = s_e + dv[j];                                                 \
      float t = fmaxf(lg, LRELU_ALPHA * lg);                                  \
      float e = ((m8 >> j) & 1) ? __expf(-t) : 0.f;                           \
      racc += e;                                                              \
      ev[j] = f2bf(e);                                                        \
    }                                                                         \
    *(u16x4v*)&At[BUFA][er * 32 + c8 * 4] = ev;                               \
  }

#define COMPUTE(BUFB, BUFA)                                                   \
  {                                                                           \
    bf16x8 af0 = __builtin_bit_cast(bf16x8,                                   \
        *(const int4v*)&At[BUFA][atoff0]);                                    \
    bf16x8 af1 = __builtin_bit_cast(bf16x8,                                   \
        *(const int4v*)&At[BUFA][atoff1]);                                    \
    _Pragma("unroll")                                                         \
    for (int n = 0; n < 4; ++n) {                                             \
      bf16x8 bfv = __builtin_bit_cast(bf16x8,                                 \
          *(const int4v*)&Bt[BUFB][btoff + n * 512]);                         \
      acc0[n] = __builtin_amdgcn_mfma_f32_16x16x32_bf16(af0, bfv, acc0[n],    \
                                                        0, 0, 0);             \
      acc1[n] = __builtin_amdgcn_mfma_f32_16x16x32_bf16(af1, bfv, acc1[n],    \
                                                        0, 0, 0);             \
    }                                                                         \
  }

#define WAITS(VN)                                                             \
    asm volatile("s_waitcnt lgkmcnt(0)" ::: "memory");                        \
    asm volatile("s_waitcnt vmcnt(" #VN ")" ::: "memory");                    \
    __builtin_amdgcn_s_barrier();

  // prologue: issue B steps 0..2; publish mask/d; e-gen step 0
  ISSUE(0, 0)
  ISSUE(1, 1)
  ISSUE(2, 2)
  __syncthreads();                 // Mk/Dl visible (full drain once: OK)
  EGEN(0, 0)
  asm volatile("s_waitcnt lgkmcnt(0)" ::: "memory");
  __builtin_amdgcn_s_barrier();

  // steady state: step j computes (Bt[j&3], At[j&1]); issues B step j+3;
  // e-gens step j+1. vmcnt(4) leaves steps j+2,j+3 in flight.
  for (int k = 0; k < 124; k += 4) {
    ISSUE(3, k + 3) EGEN(1, k + 1) COMPUTE(0, 0) WAITS(4)
    ISSUE(0, k + 4) EGEN(0, k + 2) COMPUTE(1, 1) WAITS(4)
    ISSUE(1, k + 5) EGEN(1, k + 3) COMPUTE(2, 0) WAITS(4)
    ISSUE(2, k + 6) EGEN(0, k + 4) COMPUTE(3, 1) WAITS(4)
  }
  // tail: steps 124..127
  ISSUE(3, 127) EGEN(1, 125) COMPUTE(0, 0) WAITS(4)
  EGEN(0, 126) COMPUTE(1, 1) WAITS(2)
  EGEN(1, 127) COMPUTE(2, 0) WAITS(0)
  COMPUTE(3, 1)
#undef ISSUE
#undef EGEN
#undef COMPUTE
#undef WAITS

  // ---- rowsum: c8-partials within each row (owned by one wave) ----
  racc += __shfl_xor(racc, 1);
  racc += __shfl_xor(racc, 2);
  racc += __shfl_xor(racc, 4);
  if (c8 == 0) rs_lds[er] = (racc == 0.f) ? 1.f : racc;
  __syncthreads();

  // ---- epilogue: divide + elu + store ----
#pragma unroll
  for (int t16 = 0; t16 < 2; ++t16) {
#pragma unroll
    for (int n = 0; n < 4; ++n) {
#pragma unroll
      for (int reg = 0; reg < 4; ++reg) {
        int rloc = 32 * wr + 16 * t16 + lkg * 4 + reg;
        int col = 64 * wc + 16 * n + lr;
        float v = (t16 ? acc1[n][reg] : acc0[n][reg]) / rs_lds[rloc];
        out[((size_t)(b * 4096 + rowbase + rloc)) * 256 + col] =
            v > 0.f ? v : (__expf(v) - 1.f);
      }
    }
  }
}

extern "C" void kernel_launch(void* const* d_in, const int* in_sizes, int n_in,
                              void* d_out, int out_size, void* d_ws, size_t ws_size,
                              hipStream_t stream) {
  const float* h = (const float*)d_in[0];
  const int* adj = (const int*)d_in[1];
  const float* W = (const float*)d_in[2];
  const float* a = (const float*)d_in[3];
  float* out = (float*)d_out;

  u16* WbT   = (u16*)d_ws;                                   // 128 KB
  u16* HhTt  = (u16*)((char*)d_ws + 131072);                 // 8 MB
  float* sb  = (float*)((char*)d_ws + 131072 + 8388608);     // 64 KB
  float* db  = sb + 16384;                                   // 64 KB
  u32* maskg = (u32*)((char*)d_ws + 131072 + 8388608 + 131072);  // 8 MB

  hipLaunchKernelGGL(wcast,    dim3(256),  dim3(256), 0, stream, W, WbT);
  hipLaunchKernelGGL(packadj,  dim3(2048), dim3(256), 0, stream, adj, maskg);
  hipLaunchKernelGGL(gemm1,    dim3(256),  dim3(256), 0, stream, h, WbT, a, HhTt, sb, db);
  hipLaunchKernelGGL(gat_main, dim3(256),  dim3(512), 0, stream, maskg, HhTt, sb, db, out);
}